// Round 2
// baseline (1098.737 us; speedup 1.0000x reference)
//
#include <hip/hip_runtime.h>
#include <stdint.h>

#define NROWS 16384            // 16*32*32 flattened rows
#define KCODES 8192
#define DIM 256
#define HW 1024                // 32*32
#define CHW (DIM*HW)           // 262144
#define IDX_OFF 4194304        // 16*256*32*32
#define LOSS_OFF 4210688       // IDX_OFF + 16384

typedef unsigned long long u64;

__device__ __forceinline__ unsigned int forder(float f) {
    unsigned int u = __float_as_uint(f);
    return (u & 0x80000000u) ? ~u : (u | 0x80000000u);
}

// ws layout: [0, NROWS) u64 argmin keys ; then NROWS floats of fl32(||f||^2)
__global__ void init_kernel(u64* __restrict__ keys, float* __restrict__ out) {
    int i = blockIdx.x * 256 + threadIdx.x;
    if (i < NROWS) keys[i] = 0xFFFFFFFFFFFFFFFFULL;
    if (i == 0) out[LOSS_OFF] = 0.0f;   // out is poisoned before every launch
}

// fl32(||f||^2) per row, emulating numpy pairwise_sum for n=256 bit-exactly:
// split 128+128; each half: 8 accumulators r0..r7, serial blocks of 8, then
// ((r0+r1)+(r2+r3))+((r4+r5)+(r6+r7)); total = left + right.
// __fmul_rn/__fadd_rn prevent fma contraction / reassociation.
__global__ __launch_bounds__(256)
void rownorm_kernel(const float* __restrict__ hs, float* __restrict__ rn) {
    int b  = blockIdx.x >> 2;                       // 16 batches * 4 blocks
    int hw = ((blockIdx.x & 3) << 8) + threadIdx.x; // 0..1023
    const float* p = hs + (size_t)b * CHW + hw;     // stride HW along channels
    float half[2];
    #pragma unroll
    for (int h = 0; h < 2; ++h) {
        float r[8];
        #pragma unroll
        for (int j = 0; j < 8; ++j) {
            float v = p[(size_t)(h * 128 + j) * HW];
            r[j] = __fmul_rn(v, v);
        }
        for (int i = 8; i < 128; i += 8) {
            #pragma unroll
            for (int j = 0; j < 8; ++j) {
                float v = p[(size_t)(h * 128 + i + j) * HW];
                r[j] = __fadd_rn(r[j], __fmul_rn(v, v));
            }
        }
        half[h] = __fadd_rn(__fadd_rn(__fadd_rn(r[0], r[1]), __fadd_rn(r[2], r[3])),
                            __fadd_rn(__fadd_rn(r[4], r[5]), __fadd_rn(r[6], r[7])));
    }
    rn[b * HW + hw] = __fadd_rn(half[0], half[1]);
}

// 64 rows x 64 codes per block, 4x4 per thread.
// Score replicates ref rounding: s = fl32( rn_row - 2*dot ) ; ||e||^2 term is
// provably lost in the ref's own rounding (|C| < ulp(s)/2), so omitted.
// Ties (frequent on the quantized grid) break to lowest code index via the
// (score,index) u64 min — matching np.argmin first-occurrence semantics.
__global__ __launch_bounds__(256)
void gemm_argmin(const float* __restrict__ hs, const float* __restrict__ cb,
                 const float* __restrict__ rn, u64* __restrict__ keys) {
    __shared__ float  As[64][68];     // [c][row], pad 68: b128-aligned, conflict-free
    __shared__ float4 Bs4[64 * 16];   // [c][code-group], xor-swizzled float4

    const int tid  = threadIdx.x;
    const int n0   = blockIdx.x << 6;         // row base
    const int code0= blockIdx.y << 6;         // code base
    const int bb   = n0 >> 10;                // batch (64 | 1024 so no crossing)
    const int hw0  = n0 & 1023;
    const float* hsb = hs + (size_t)bb * CHW + hw0;

    const int tx = tid & 15, ty = tid >> 4;   // 16x16 threads -> 4x4 tiles
    const int i4  = tid & 15, cc0 = tid >> 4; // A-staging mapping
    const int li  = tid & 63, lw  = tid >> 6; // B-staging mapping

    float acc[4][4];
    #pragma unroll
    for (int i = 0; i < 4; ++i)
        #pragma unroll
        for (int j = 0; j < 4; ++j) acc[i][j] = 0.0f;

    for (int kc = 0; kc < DIM; kc += 64) {
        #pragma unroll
        for (int j = 0; j < 4; ++j) {
            int cc = cc0 + (j << 4);
            float4 gv = *(const float4*)&hsb[(size_t)(kc + cc) * HW + (i4 << 2)];
            *(float4*)&As[cc][i4 << 2] = gv;
        }
        #pragma unroll
        for (int j = 0; j < 4; ++j) {
            int g = lw + (j << 2);
            const float* p = cb + (size_t)(code0 + (g << 2)) * DIM + kc + li;
            float4 v;
            v.x = p[0]; v.y = p[DIM]; v.z = p[2 * DIM]; v.w = p[3 * DIM];
            Bs4[(li << 4) + (g ^ (li & 15))] = v;
        }
        __syncthreads();
        #pragma unroll 8
        for (int k = 0; k < 64; ++k) {
            float4 av = *(const float4*)&As[k][ty << 2];
            float4 bv = Bs4[(k << 4) + (tx ^ (k & 15))];
            acc[0][0] += av.x * bv.x; acc[0][1] += av.x * bv.y; acc[0][2] += av.x * bv.z; acc[0][3] += av.x * bv.w;
            acc[1][0] += av.y * bv.x; acc[1][1] += av.y * bv.y; acc[1][2] += av.y * bv.z; acc[1][3] += av.y * bv.w;
            acc[2][0] += av.z * bv.x; acc[2][1] += av.z * bv.y; acc[2][2] += av.z * bv.z; acc[2][3] += av.z * bv.w;
            acc[3][0] += av.w * bv.x; acc[3][1] += av.w * bv.y; acc[3][2] += av.w * bv.z; acc[3][3] += av.w * bv.w;
        }
        __syncthreads();
    }

    #pragma unroll
    for (int i = 0; i < 4; ++i) {
        float rn_i = rn[n0 + (ty << 2) + i];
        // s = fl(rn - 2*acc): doubling is exact, so fma-or-not is bit-identical
        float best = __fadd_rn(rn_i, -2.0f * acc[i][0]);
        int bidx = code0 + (tx << 2);
        #pragma unroll
        for (int j = 1; j < 4; ++j) {
            float s = __fadd_rn(rn_i, -2.0f * acc[i][j]);
            int cand = code0 + (tx << 2) + j;
            if (s < best) { best = s; bidx = cand; }   // strict <: lowest idx on tie
        }
        u64 key = ((u64)forder(best) << 32) | (u64)bidx;
        #pragma unroll
        for (int m = 1; m < 16; m <<= 1) {
            u64 other = __shfl_xor(key, m, 64);   // within tx-group (same ty)
            if (other < key) key = other;
        }
        if (tx == 0) atomicMin(&keys[n0 + (ty << 2) + i], key);
    }
}

// block = (batch b, channel c); threads over hw. Coalesced x/out, gathered codebook.
__global__ __launch_bounds__(256)
void gather_kernel(const float* __restrict__ hs, const float* __restrict__ cb,
                   const u64* __restrict__ keys, float* __restrict__ out) {
    int b = blockIdx.x;          // 0..15
    int c = blockIdx.y;          // 0..255
    int t = threadIdx.x;         // 0..255 -> hw = 4t..4t+3
    int nbase = b * HW + (t << 2);

    int codes[4]; float q[4];
    #pragma unroll
    for (int u = 0; u < 4; ++u) {
        u64 k = keys[nbase + u];
        codes[u] = (int)(k & 0xFFFFFFFFULL);
        q[u] = cb[(size_t)codes[u] * DIM + c];
    }
    size_t off = (size_t)b * CHW + (size_t)c * HW;
    float4 xv = ((const float4*)(hs + off))[t];
    float4 qv;
    qv.x = xv.x + (q[0] - xv.x);
    qv.y = xv.y + (q[1] - xv.y);
    qv.z = xv.z + (q[2] - xv.z);
    qv.w = xv.w + (q[3] - xv.w);
    ((float4*)(out + off))[t] = qv;

    float d0 = q[0] - xv.x, d1 = q[1] - xv.y, d2 = q[2] - xv.z, d3 = q[3] - xv.w;
    float s = d0*d0 + d1*d1 + d2*d2 + d3*d3;
    #pragma unroll
    for (int m = 32; m >= 1; m >>= 1) s += __shfl_xor(s, m, 64);
    __shared__ float red[4];
    if ((t & 63) == 0) red[t >> 6] = s;
    __syncthreads();
    if (t == 0) {
        float tot = red[0] + red[1] + red[2] + red[3];
        atomicAdd(out + LOSS_OFF, tot * (1.25f / 4194304.0f));  // (1+0.25)*mean
    }
    if (c == 0) {
        #pragma unroll
        for (int u = 0; u < 4; ++u)
            out[IDX_OFF + nbase + u] = (float)codes[u];
    }
}

extern "C" void kernel_launch(void* const* d_in, const int* in_sizes, int n_in,
                              void* d_out, int out_size, void* d_ws, size_t ws_size,
                              hipStream_t stream) {
    const float* hs = (const float*)d_in[0];   // (16,256,32,32) f32
    const float* cb = (const float*)d_in[1];   // (8192,256) f32
    float* out = (float*)d_out;
    u64*   keys = (u64*)d_ws;
    float* rn   = (float*)((char*)d_ws + (size_t)NROWS * sizeof(u64));

    init_kernel<<<NROWS / 256, 256, 0, stream>>>(keys, out);
    rownorm_kernel<<<64, 256, 0, stream>>>(hs, rn);
    gemm_argmin<<<dim3(NROWS / 64, KCODES / 64), 256, 0, stream>>>(hs, cb, rn, keys);
    gather_kernel<<<dim3(16, DIM), 256, 0, stream>>>(hs, cb, keys, out);
}

// Round 3
// 906.893 us; speedup vs baseline: 1.2115x; 1.2115x over previous
//
#include <hip/hip_runtime.h>
#include <stdint.h>

#define NROWS 16384            // 16*32*32 flattened rows
#define KCODES 8192
#define DIM 256
#define HW 1024                // 32*32
#define CHW (DIM*HW)           // 262144
#define IDX_OFF 4194304        // 16*256*32*32
#define LOSS_OFF 4210688       // IDX_OFF + 16384

typedef unsigned long long u64;

__device__ __forceinline__ unsigned int forder(float f) {
    unsigned int u = __float_as_uint(f);
    return (u & 0x80000000u) ? ~u : (u | 0x80000000u);
}

// ws layout: [0, NROWS) u64 argmin keys ; then NROWS floats of fl32(||f||^2)
// fl32(||f||^2) per row, emulating numpy pairwise_sum for n=256 bit-exactly:
// split 128+128; each half: 8 accumulators, serial blocks of 8, then
// ((r0+r1)+(r2+r3))+((r4+r5)+(r6+r7)); total = left + right.
// Also initializes the argmin keys and the loss slot (poisoned every launch).
__global__ __launch_bounds__(256)
void rownorm_kernel(const float* __restrict__ hs, float* __restrict__ rn,
                    u64* __restrict__ keys, float* __restrict__ out) {
    int gid = blockIdx.x * 256 + threadIdx.x;   // 0..16383 == row id
    keys[gid] = 0xFFFFFFFFFFFFFFFFULL;
    if (gid == 0) out[LOSS_OFF] = 0.0f;

    int b  = blockIdx.x >> 2;                       // 16 batches * 4 blocks
    int hw = ((blockIdx.x & 3) << 8) + threadIdx.x; // 0..1023
    const float* p = hs + (size_t)b * CHW + hw;     // stride HW along channels
    float half[2];
    #pragma unroll
    for (int h = 0; h < 2; ++h) {
        float r[8];
        #pragma unroll
        for (int j = 0; j < 8; ++j) {
            float v = p[(size_t)(h * 128 + j) * HW];
            r[j] = __fmul_rn(v, v);
        }
        for (int i = 8; i < 128; i += 8) {
            #pragma unroll
            for (int j = 0; j < 8; ++j) {
                float v = p[(size_t)(h * 128 + i + j) * HW];
                r[j] = __fadd_rn(r[j], __fmul_rn(v, v));
            }
        }
        half[h] = __fadd_rn(__fadd_rn(__fadd_rn(r[0], r[1]), __fadd_rn(r[2], r[3])),
                            __fadd_rn(__fadd_rn(r[4], r[5]), __fadd_rn(r[6], r[7])));
    }
    rn[b * HW + hw] = __fadd_rn(half[0], half[1]);
}

// 128 rows x 128 codes per block, 8x8 per thread, BK=32.
// BIT-EXACTNESS INVARIANT: each (row,code) dot is a sequential k=0..255 fp32
// fma chain (fmaf), identical operand values/order to the previously-passing
// kernel; score = fl32(rn_row - 2*dot); ties -> lowest code index.
__global__ __launch_bounds__(256, 4)
void gemm_argmin(const float* __restrict__ hs, const float* __restrict__ cb,
                 const float* __restrict__ rn, u64* __restrict__ keys) {
    __shared__ float As[32][132];   // [k][row], pad 132: stores conflict-light
    __shared__ float Bs[32][132];   // [k][code]

    const int tid   = threadIdx.x;
    const int n0    = blockIdx.x << 7;        // row base (128)
    const int code0 = blockIdx.y << 7;        // code base (128)
    const int bb    = n0 >> 10;               // batch (128 | 1024: no crossing)
    const int hw0   = n0 & 1023;
    const float* hsb = hs + (size_t)bb * CHW + hw0;

    const int tx = tid & 15;                  // code group: 8 codes at tx*8
    const int tyg = tid >> 4;                 // row group: 8 rows at tyg*8
    const int ry = tyg << 3;
    const int cx = tx << 3;

    float acc[8][8];
    #pragma unroll
    for (int i = 0; i < 8; ++i)
        #pragma unroll
        for (int j = 0; j < 8; ++j) acc[i][j] = 0.0f;

    // staging maps
    const int a_c0 = tid >> 5;                // 0..7  (channel, +8*j)
    const int a_rg = tid & 31;                // row group of 4
    const int b_code0 = tid >> 3;             // 0..31 (code, +32*j)
    const int b_cch   = (tid & 7) << 2;       // channel chunk of 4

    for (int kc = 0; kc < DIM; kc += 32) {
        #pragma unroll
        for (int j = 0; j < 4; ++j) {
            int c = a_c0 + (j << 3);
            float4 gv = *(const float4*)&hsb[(size_t)(kc + c) * HW + (a_rg << 2)];
            *(float4*)&As[c][a_rg << 2] = gv;
        }
        #pragma unroll
        for (int j = 0; j < 4; ++j) {
            int code = b_code0 + (j << 5);
            float4 v = *(const float4*)&cb[(size_t)(code0 + code) * DIM + kc + b_cch];
            Bs[b_cch + 0][code] = v.x;
            Bs[b_cch + 1][code] = v.y;
            Bs[b_cch + 2][code] = v.z;
            Bs[b_cch + 3][code] = v.w;
        }
        __syncthreads();
        #pragma unroll 4
        for (int k = 0; k < 32; ++k) {
            float4 a0 = *(const float4*)&As[k][ry];
            float4 a1 = *(const float4*)&As[k][ry + 4];
            float4 b0 = *(const float4*)&Bs[k][cx];
            float4 b1 = *(const float4*)&Bs[k][cx + 4];
            float a[8] = {a0.x, a0.y, a0.z, a0.w, a1.x, a1.y, a1.z, a1.w};
            float bq[8] = {b0.x, b0.y, b0.z, b0.w, b1.x, b1.y, b1.z, b1.w};
            #pragma unroll
            for (int i = 0; i < 8; ++i)
                #pragma unroll
                for (int j = 0; j < 8; ++j)
                    acc[i][j] = fmaf(a[i], bq[j], acc[i][j]);
        }
        __syncthreads();
    }

    #pragma unroll
    for (int i = 0; i < 8; ++i) {
        int row = n0 + ry + i;
        float rn_i = rn[row];
        float best = __fadd_rn(rn_i, -2.0f * acc[i][0]);
        int bidx = code0 + cx;
        #pragma unroll
        for (int j = 1; j < 8; ++j) {
            float s = __fadd_rn(rn_i, -2.0f * acc[i][j]);
            if (s < best) { best = s; bidx = code0 + cx + j; }  // strict <
        }
        u64 key = ((u64)forder(best) << 32) | (u64)bidx;
        #pragma unroll
        for (int m = 1; m < 16; m <<= 1) {
            u64 other = __shfl_xor(key, m, 64);   // within 16-lane tx-group
            if (other < key) key = other;
        }
        if (tx == 0) atomicMin(&keys[row], key);
    }
}

// block = (batch b, channel c); threads over hw. Coalesced x/out, gathered codebook.
__global__ __launch_bounds__(256)
void gather_kernel(const float* __restrict__ hs, const float* __restrict__ cb,
                   const u64* __restrict__ keys, float* __restrict__ out) {
    int b = blockIdx.x;          // 0..15
    int c = blockIdx.y;          // 0..255
    int t = threadIdx.x;         // 0..255 -> hw = 4t..4t+3
    int nbase = b * HW + (t << 2);

    int codes[4]; float q[4];
    #pragma unroll
    for (int u = 0; u < 4; ++u) {
        u64 k = keys[nbase + u];
        codes[u] = (int)(k & 0xFFFFFFFFULL);
        q[u] = cb[(size_t)codes[u] * DIM + c];
    }
    size_t off = (size_t)b * CHW + (size_t)c * HW;
    float4 xv = ((const float4*)(hs + off))[t];
    float4 qv;
    qv.x = xv.x + (q[0] - xv.x);
    qv.y = xv.y + (q[1] - xv.y);
    qv.z = xv.z + (q[2] - xv.z);
    qv.w = xv.w + (q[3] - xv.w);
    ((float4*)(out + off))[t] = qv;

    float d0 = q[0] - xv.x, d1 = q[1] - xv.y, d2 = q[2] - xv.z, d3 = q[3] - xv.w;
    float s = d0*d0 + d1*d1 + d2*d2 + d3*d3;
    #pragma unroll
    for (int m = 32; m >= 1; m >>= 1) s += __shfl_xor(s, m, 64);
    __shared__ float red[4];
    if ((t & 63) == 0) red[t >> 6] = s;
    __syncthreads();
    if (t == 0) {
        float tot = red[0] + red[1] + red[2] + red[3];
        atomicAdd(out + LOSS_OFF, tot * (1.25f / 4194304.0f));  // (1+0.25)*mean
    }
    if (c == 0) {
        #pragma unroll
        for (int u = 0; u < 4; ++u)
            out[IDX_OFF + nbase + u] = (float)codes[u];
    }
}

extern "C" void kernel_launch(void* const* d_in, const int* in_sizes, int n_in,
                              void* d_out, int out_size, void* d_ws, size_t ws_size,
                              hipStream_t stream) {
    const float* hs = (const float*)d_in[0];   // (16,256,32,32) f32
    const float* cb = (const float*)d_in[1];   // (8192,256) f32
    float* out = (float*)d_out;
    u64*   keys = (u64*)d_ws;
    float* rn   = (float*)((char*)d_ws + (size_t)NROWS * sizeof(u64));

    rownorm_kernel<<<64, 256, 0, stream>>>(hs, rn, keys, out);
    gemm_argmin<<<dim3(NROWS / 128, KCODES / 128), 256, 0, stream>>>(hs, cb, rn, keys);
    gather_kernel<<<dim3(16, DIM), 256, 0, stream>>>(hs, cb, keys, out);
}

// Round 4
// 897.505 us; speedup vs baseline: 1.2242x; 1.0105x over previous
//
#include <hip/hip_runtime.h>
#include <stdint.h>

#define NROWS 16384            // 16*32*32 flattened rows
#define KCODES 8192
#define DIM 256
#define HW 1024                // 32*32
#define CHW (DIM*HW)           // 262144
#define IDX_OFF 4194304        // 16*256*32*32
#define LOSS_OFF 4210688       // IDX_OFF + 16384

typedef unsigned long long u64;

__device__ __forceinline__ unsigned int forder(float f) {
    unsigned int u = __float_as_uint(f);
    return (u & 0x80000000u) ? ~u : (u | 0x80000000u);
}

// ws layout: [0, NROWS) u64 argmin keys ; then NROWS floats of fl32(||f||^2)
// fl32(||f||^2) per row, emulating numpy pairwise_sum for n=256 bit-exactly:
// split 128+128; each half: 8 accumulators, serial blocks of 8, then
// ((r0+r1)+(r2+r3))+((r4+r5)+(r6+r7)); total = left + right.
// Also initializes the argmin keys and the loss slot (poisoned every launch).
__global__ __launch_bounds__(256)
void rownorm_kernel(const float* __restrict__ hs, float* __restrict__ rn,
                    u64* __restrict__ keys, float* __restrict__ out) {
    int gid = blockIdx.x * 256 + threadIdx.x;   // 0..16383 == row id
    keys[gid] = 0xFFFFFFFFFFFFFFFFULL;
    if (gid == 0) out[LOSS_OFF] = 0.0f;

    int b  = blockIdx.x >> 2;                       // 16 batches * 4 blocks
    int hw = ((blockIdx.x & 3) << 8) + threadIdx.x; // 0..1023
    const float* p = hs + (size_t)b * CHW + hw;     // stride HW along channels
    float half[2];
    #pragma unroll
    for (int h = 0; h < 2; ++h) {
        float r[8];
        #pragma unroll
        for (int j = 0; j < 8; ++j) {
            float v = p[(size_t)(h * 128 + j) * HW];
            r[j] = __fmul_rn(v, v);
        }
        for (int i = 8; i < 128; i += 8) {
            #pragma unroll
            for (int j = 0; j < 8; ++j) {
                float v = p[(size_t)(h * 128 + i + j) * HW];
                r[j] = __fadd_rn(r[j], __fmul_rn(v, v));
            }
        }
        half[h] = __fadd_rn(__fadd_rn(__fadd_rn(r[0], r[1]), __fadd_rn(r[2], r[3])),
                            __fadd_rn(__fadd_rn(r[4], r[5]), __fadd_rn(r[6], r[7])));
    }
    rn[b * HW + hw] = __fadd_rn(half[0], half[1]);
}

// 128 rows x 128 codes per block, 8x8 per thread (split 4+4), BK=32.
// BIT-EXACTNESS INVARIANT: each (row,code) dot is a sequential k=0..255 fp32
// fma chain, identical operand values/order to the previously-passing kernel;
// score = fl32(rn_row - 2*dot); ties -> lowest code index (in-thread scan is
// in increasing code order; cross-thread via (score,idx) u64 min).
// All LDS access patterns are bank-uniform (<=2-way): A/B compute reads are
// 2-way or broadcast; A b128 stores cover all banks evenly; B scalar stores
// hit all 32 banks x2.
__global__ __launch_bounds__(256, 4)
void gemm_argmin(const float* __restrict__ hs, const float* __restrict__ cb,
                 const float* __restrict__ rn, u64* __restrict__ keys) {
    __shared__ float As[32][132];   // [k][row], pad 132
    __shared__ float Bs[32][132];   // [k][code]

    const int tid   = threadIdx.x;
    const int n0    = blockIdx.x << 7;        // row base (128)
    const int code0 = blockIdx.y << 7;        // code base (128)
    const int bb    = n0 >> 10;               // batch (128 | 1024: no crossing)
    const int hw0   = n0 & 1023;
    const float* hsb = hs + (size_t)bb * CHW + hw0;

    const int tx  = tid & 15;                 // codes {4tx..+3} u {64+4tx..+3}
    const int tyg = tid >> 4;                 // rows  {4ty..+3} u {64+4ty..+3}
    const int ry = tyg << 2;
    const int cx = tx << 2;

    float acc[8][8];
    #pragma unroll
    for (int i = 0; i < 8; ++i)
        #pragma unroll
        for (int j = 0; j < 8; ++j) acc[i][j] = 0.0f;

    // staging maps
    const int a_c0 = tid >> 5;                // 0..7  (channel, +8*j)
    const int a_rg = tid & 31;                // row group of 4
    const int b_p  = tid & 1;                 // dim-half within 8-chunk
    const int b_cd = tid >> 1;                // code 0..127

    for (int kc = 0; kc < DIM; kc += 32) {
        #pragma unroll
        for (int j = 0; j < 4; ++j) {
            int c = a_c0 + (j << 3);
            float4 gv = *(const float4*)&hsb[(size_t)(kc + c) * HW + (a_rg << 2)];
            *(float4*)&As[c][a_rg << 2] = gv;
        }
        #pragma unroll
        for (int j = 0; j < 4; ++j) {
            int k0 = (b_p << 2) + (j << 3);   // dim-in-block 4p + 8j
            float4 v = *(const float4*)&cb[(size_t)(code0 + b_cd) * DIM + kc + k0];
            Bs[k0 + 0][b_cd] = v.x;
            Bs[k0 + 1][b_cd] = v.y;
            Bs[k0 + 2][b_cd] = v.z;
            Bs[k0 + 3][b_cd] = v.w;
        }
        __syncthreads();
        #pragma unroll 8
        for (int k = 0; k < 32; ++k) {
            float4 a0 = *(const float4*)&As[k][ry];
            float4 a1 = *(const float4*)&As[k][64 + ry];
            float4 b0 = *(const float4*)&Bs[k][cx];
            float4 b1 = *(const float4*)&Bs[k][64 + cx];
            float a[8] = {a0.x, a0.y, a0.z, a0.w, a1.x, a1.y, a1.z, a1.w};
            float bq[8] = {b0.x, b0.y, b0.z, b0.w, b1.x, b1.y, b1.z, b1.w};
            #pragma unroll
            for (int i = 0; i < 8; ++i)
                #pragma unroll
                for (int j = 0; j < 8; ++j)
                    acc[i][j] = fmaf(a[i], bq[j], acc[i][j]);
        }
        __syncthreads();
    }

    #pragma unroll
    for (int i = 0; i < 8; ++i) {
        int row = n0 + ((i < 4) ? (ry + i) : (64 + ry + i - 4));
        float rn_i = rn[row];
        float best = __fadd_rn(rn_i, -2.0f * acc[i][0]);
        int bidx = code0 + cx;
        #pragma unroll
        for (int j = 1; j < 8; ++j) {
            float s = __fadd_rn(rn_i, -2.0f * acc[i][j]);
            int cand = code0 + ((j < 4) ? (cx + j) : (64 + cx + j - 4));
            if (s < best) { best = s; bidx = cand; }  // strict <: lowest idx wins
        }
        u64 key = ((u64)forder(best) << 32) | (u64)bidx;
        #pragma unroll
        for (int m = 1; m < 16; m <<= 1) {
            u64 other = __shfl_xor(key, m, 64);   // within 16-lane tx-group
            if (other < key) key = other;
        }
        if (tx == 0) atomicMin(&keys[row], key);
    }
}

// block = (batch b, channel c); threads over hw. Coalesced x/out, gathered codebook.
__global__ __launch_bounds__(256)
void gather_kernel(const float* __restrict__ hs, const float* __restrict__ cb,
                   const u64* __restrict__ keys, float* __restrict__ out) {
    int b = blockIdx.x;          // 0..15
    int c = blockIdx.y;          // 0..255
    int t = threadIdx.x;         // 0..255 -> hw = 4t..4t+3
    int nbase = b * HW + (t << 2);

    int codes[4]; float q[4];
    #pragma unroll
    for (int u = 0; u < 4; ++u) {
        u64 k = keys[nbase + u];
        codes[u] = (int)(k & 0xFFFFFFFFULL);
        q[u] = cb[(size_t)codes[u] * DIM + c];
    }
    size_t off = (size_t)b * CHW + (size_t)c * HW;
    float4 xv = ((const float4*)(hs + off))[t];
    float4 qv;
    qv.x = xv.x + (q[0] - xv.x);
    qv.y = xv.y + (q[1] - xv.y);
    qv.z = xv.z + (q[2] - xv.z);
    qv.w = xv.w + (q[3] - xv.w);
    ((float4*)(out + off))[t] = qv;

    float d0 = q[0] - xv.x, d1 = q[1] - xv.y, d2 = q[2] - xv.z, d3 = q[3] - xv.w;
    float s = d0*d0 + d1*d1 + d2*d2 + d3*d3;
    #pragma unroll
    for (int m = 32; m >= 1; m >>= 1) s += __shfl_xor(s, m, 64);
    __shared__ float red[4];
    if ((t & 63) == 0) red[t >> 6] = s;
    __syncthreads();
    if (t == 0) {
        float tot = red[0] + red[1] + red[2] + red[3];
        atomicAdd(out + LOSS_OFF, tot * (1.25f / 4194304.0f));  // (1+0.25)*mean
    }
    if (c == 0) {
        #pragma unroll
        for (int u = 0; u < 4; ++u)
            out[IDX_OFF + nbase + u] = (float)codes[u];
    }
}

extern "C" void kernel_launch(void* const* d_in, const int* in_sizes, int n_in,
                              void* d_out, int out_size, void* d_ws, size_t ws_size,
                              hipStream_t stream) {
    const float* hs = (const float*)d_in[0];   // (16,256,32,32) f32
    const float* cb = (const float*)d_in[1];   // (8192,256) f32
    float* out = (float*)d_out;
    u64*   keys = (u64*)d_ws;
    float* rn   = (float*)((char*)d_ws + (size_t)NROWS * sizeof(u64));

    rownorm_kernel<<<64, 256, 0, stream>>>(hs, rn, keys, out);
    gemm_argmin<<<dim3(NROWS / 128, KCODES / 128), 256, 0, stream>>>(hs, cb, rn, keys);
    gather_kernel<<<dim3(16, DIM), 256, 0, stream>>>(hs, cb, keys, out);
}